// Round 1
// baseline (216.639 us; speedup 1.0000x reference)
//
#include <hip/hip_runtime.h>
#include <math.h>

// EdgeConvGNN: 2-layer GCN on a line graph, but the output is a single
// scalar sigmoid(h2[index01] . Wl + bl). Only the 2-hop neighborhood of
// index01 (plus the global degree histogram) is live. We therefore:
//   K1: full scan of lg col[] -> deg histogram + collect edges with col==idx0
//   K2: dedup -> S2 = {idx0} U rows(list1)
//   K3: full scan -> collect edges with col in S2 (list2)
//   K4: dedup -> S3 = rows(list2) U S2   (nodes needing hw0 = h0 @ W0)
//   K5: hw0[slot] = concat(x[src],x[dst]) @ W0  (one block per S3 node)
//   K6: h1[s2pos] = relu(aggregate(list2) + self + b0)
//   K7: hw1 = h1 @ W1
//   K8: h2 = relu(aggregate(list1) + self + b1); out = sigmoid(h2.Wl + bl)

#define MAX_L1 1024
#define MAX_S2 1024
#define MAX_L2 8192
#define MAX_S3 8192

enum { CNT_L1 = 0, CNT_S2 = 1, CNT_L2 = 2, CNT_S3 = 3 };

__global__ void k_deg_l1(const int* __restrict__ lg, int e_lg,
                         const int* __restrict__ pidx,
                         int* __restrict__ deg, int* __restrict__ list1,
                         int* __restrict__ cnt) {
  const int idx0 = pidx[0];
  const int* col = lg + e_lg;
  const int stride = gridDim.x * blockDim.x;
  for (int e = blockIdx.x * blockDim.x + threadIdx.x; e < e_lg; e += stride) {
    int c = col[e];
    atomicAdd(&deg[c], 1);
    if (c == idx0) {
      int p = atomicAdd(&cnt[CNT_L1], 1);
      if (p < MAX_L1) list1[p] = lg[e];  // row endpoint
    }
  }
}

__global__ void k_build_s2(const int* __restrict__ list1,
                           const int* __restrict__ pidx,
                           int* __restrict__ flag2, int* __restrict__ s2_list,
                           int* __restrict__ s2pos, int* __restrict__ cnt) {
  const int idx0 = pidx[0];
  int n1 = min(cnt[CNT_L1], MAX_L1);
  for (int i = threadIdx.x; i < n1 + 1; i += blockDim.x) {
    int n = (i == 0) ? idx0 : list1[i - 1];
    if (atomicExch(&flag2[n], 1) == 0) {
      int p = atomicAdd(&cnt[CNT_S2], 1);
      s2_list[p] = n;
      s2pos[n] = p;
    }
  }
}

__global__ void k_collect_l2(const int* __restrict__ lg, int e_lg,
                             const int* __restrict__ flag2,
                             int2* __restrict__ list2, int* __restrict__ cnt) {
  const int* col = lg + e_lg;
  const int stride = gridDim.x * blockDim.x;
  for (int e = blockIdx.x * blockDim.x + threadIdx.x; e < e_lg; e += stride) {
    int c = col[e];
    if (flag2[c]) {
      int p = atomicAdd(&cnt[CNT_L2], 1);
      if (p < MAX_L2) list2[p] = make_int2(lg[e], c);
    }
  }
}

__global__ void k_build_s3(const int2* __restrict__ list2,
                           const int* __restrict__ s2_list,
                           int* __restrict__ flag3, int* __restrict__ s3_list,
                           int* __restrict__ slot, int* __restrict__ cnt) {
  int n2 = min(cnt[CNT_L2], MAX_L2);
  int ns2 = min(cnt[CNT_S2], MAX_S2);
  int total = n2 + ns2;
  const int stride = gridDim.x * blockDim.x;
  for (int i = blockIdx.x * blockDim.x + threadIdx.x; i < total; i += stride) {
    int n = (i < n2) ? list2[i].x : s2_list[i - n2];
    if (atomicExch(&flag3[n], 1) == 0) {
      int p = atomicAdd(&cnt[CNT_S3], 1);
      s3_list[p] = n;
      slot[n] = p;
    }
  }
}

// one block (128 threads) per S3 node: hw0 = concat(x[src],x[dst]) @ W0
__global__ void k_hw0(const float* __restrict__ x, const int* __restrict__ g,
                      int e_g, const float* __restrict__ W0,
                      const int* __restrict__ s3_list, const int* __restrict__ cnt,
                      float* __restrict__ hw0) {
  int nb = min(cnt[CNT_S3], MAX_S3);
  int b = blockIdx.x;
  if (b >= nb) return;
  int node = s3_list[b];
  int src = g[node];
  int dst = g[e_g + node];
  __shared__ float h0[128];
  int t = threadIdx.x;
  h0[t] = (t < 64) ? x[src * 64 + t] : x[dst * 64 + (t - 64)];
  __syncthreads();
  float acc = 0.f;
#pragma unroll 8
  for (int k = 0; k < 128; ++k) acc += h0[k] * W0[k * 128 + t];
  hw0[b * 128 + t] = acc;
}

// one block per S2 node: h1 = relu(sum_{e in list2, col==j} hw0[row]*norm
//                                  + hw0[j]*dinv_j^2 + b0)
__global__ void k_h1(const float* __restrict__ hw0, const int* __restrict__ deg,
                     const int2* __restrict__ list2,
                     const int* __restrict__ s2_list, const int* __restrict__ slot,
                     const int* __restrict__ cnt, const float* __restrict__ b0,
                     float* __restrict__ h1) {
  int ns2 = min(cnt[CNT_S2], MAX_S2);
  int b = blockIdx.x;
  if (b >= ns2) return;
  int j = s2_list[b];
  int t = threadIdx.x;
  float dj = rsqrtf((float)deg[j] + 1.0f);
  float acc = hw0[slot[j] * 128 + t] * dj * dj;  // self-loop
  int n2 = min(cnt[CNT_L2], MAX_L2);
  for (int i = 0; i < n2; ++i) {
    int2 e = list2[i];
    if (e.y == j) {
      float dr = rsqrtf((float)deg[e.x] + 1.0f);
      acc += hw0[slot[e.x] * 128 + t] * (dr * dj);
    }
  }
  acc += b0[t];
  h1[b * 128 + t] = fmaxf(acc, 0.f);
}

// one block per S2 node: hw1 = h1 @ W1
__global__ void k_hw1(const float* __restrict__ h1, const float* __restrict__ W1,
                      const int* __restrict__ cnt, float* __restrict__ hw1) {
  int ns2 = min(cnt[CNT_S2], MAX_S2);
  int b = blockIdx.x;
  if (b >= ns2) return;
  __shared__ float hrow[128];
  int t = threadIdx.x;
  hrow[t] = h1[b * 128 + t];
  __syncthreads();
  float acc = 0.f;
#pragma unroll 8
  for (int k = 0; k < 128; ++k) acc += hrow[k] * W1[k * 128 + t];
  hw1[b * 128 + t] = acc;
}

__global__ void k_final(const float* __restrict__ hw1, const int* __restrict__ deg,
                        const int* __restrict__ list1, const int* __restrict__ s2pos,
                        const int* __restrict__ cnt, const int* __restrict__ pidx,
                        const float* __restrict__ b1, const float* __restrict__ Wl,
                        const float* __restrict__ bl, float* __restrict__ out) {
  int t = threadIdx.x;  // 128 threads
  int j0 = pidx[0];
  float d0 = rsqrtf((float)deg[j0] + 1.0f);
  float acc = hw1[s2pos[j0] * 128 + t] * d0 * d0;  // self-loop
  int n1 = min(cnt[CNT_L1], MAX_L1);
  for (int i = 0; i < n1; ++i) {
    int r = list1[i];
    float dr = rsqrtf((float)deg[r] + 1.0f);
    acc += hw1[s2pos[r] * 128 + t] * (dr * d0);
  }
  acc += b1[t];
  float h2 = fmaxf(acc, 0.f);
  __shared__ float red[128];
  red[t] = h2 * Wl[t];
  __syncthreads();
  for (int s = 64; s > 0; s >>= 1) {
    if (t < s) red[t] += red[t + s];
    __syncthreads();
  }
  if (t == 0) {
    float z = red[0] + bl[0];
    out[0] = 1.f / (1.f + expf(-z));
  }
}

extern "C" void kernel_launch(void* const* d_in, const int* in_sizes, int n_in,
                              void* d_out, int out_size, void* d_ws, size_t ws_size,
                              hipStream_t stream) {
  const float* x   = (const float*)d_in[0];
  const int* g     = (const int*)d_in[1];
  const int* lg    = (const int*)d_in[2];
  const int* pidx  = (const int*)d_in[3];
  const float* W0  = (const float*)d_in[4];
  const float* b0  = (const float*)d_in[5];
  const float* W1  = (const float*)d_in[6];
  const float* b1  = (const float*)d_in[7];
  const float* Wl  = (const float*)d_in[8];
  const float* bl  = (const float*)d_in[9];
  float* out = (float*)d_out;

  const int e_g = in_sizes[1] / 2;    // 200000
  const int e_lg = in_sizes[2] / 2;   // 2000000

  // ---- workspace layout (16B-aligned slabs) ----
  char* ws = (char*)d_ws;
  size_t off = 0;
  auto take = [&](size_t bytes) {
    size_t cur = off;
    off = (off + bytes + 15) & ~(size_t)15;
    return cur;
  };
  int* deg     = (int*)(ws + take((size_t)e_g * 4));
  int* flag2   = (int*)(ws + take((size_t)e_g * 4));
  int* flag3   = (int*)(ws + take((size_t)e_g * 4));
  int* cnt     = (int*)(ws + take(16 * 4));
  size_t zero_bytes = off;            // everything above must start at 0
  int* list1   = (int*)(ws + take(MAX_L1 * 4));
  int* s2_list = (int*)(ws + take(MAX_S2 * 4));
  int2* list2  = (int2*)(ws + take((size_t)MAX_L2 * 8));
  int* s3_list = (int*)(ws + take(MAX_S3 * 4));
  int* slot    = (int*)(ws + take((size_t)e_g * 4));
  int* s2pos   = (int*)(ws + take((size_t)e_g * 4));
  float* hw0   = (float*)(ws + take((size_t)MAX_S3 * 128 * 4));
  float* h1    = (float*)(ws + take((size_t)MAX_S2 * 128 * 4));
  float* hw1   = (float*)(ws + take((size_t)MAX_S2 * 128 * 4));
  (void)ws_size;

  hipMemsetAsync(d_ws, 0, zero_bytes, stream);

  k_deg_l1<<<2048, 256, 0, stream>>>(lg, e_lg, pidx, deg, list1, cnt);
  k_build_s2<<<1, 256, 0, stream>>>(list1, pidx, flag2, s2_list, s2pos, cnt);
  k_collect_l2<<<2048, 256, 0, stream>>>(lg, e_lg, flag2, list2, cnt);
  k_build_s3<<<64, 256, 0, stream>>>(list2, s2_list, flag3, s3_list, slot, cnt);
  k_hw0<<<MAX_S3, 128, 0, stream>>>(x, g, e_g, W0, s3_list, cnt, hw0);
  k_h1<<<MAX_S2, 128, 0, stream>>>(hw0, deg, list2, s2_list, slot, cnt, b0, h1);
  k_hw1<<<MAX_S2, 128, 0, stream>>>(h1, W1, cnt, hw1);
  k_final<<<1, 128, 0, stream>>>(hw1, deg, list1, s2pos, cnt, pidx, b1, Wl, bl, out);
}